// Round 2
// baseline (101.937 us; speedup 1.0000x reference)
//
#include <hip/hip_runtime.h>
#include <math.h>

static constexpr int TLEN   = 1024;  // signal length
static constexpr int NSAMP  = 1022;  // N = T - M, M = 2
static constexpr int NCHUNK = 17;    // ceil(1021 / 62) row-chunks per signal
static constexpr int NSIG   = 128;   // 64 pred + 64 targ
static constexpr float RTHR = 0.2f;
static constexpr float EPSN = 1e-8f;
// credit bits 0..61 of each 64-bit ballot; chunks stride by 62 -> no overlap
static constexpr unsigned long long MCRED = 0x3FFFFFFFFFFFFFFFULL;

__device__ __forceinline__ float wave_sum_f(float v) {
#pragma unroll
  for (int off = 32; off > 0; off >>= 1) v += __shfl_down(v, off);
  return v;
}

// grid (NCHUNK, NSIG), 256 threads (4 waves).
// Phase 1: in-block normalize (reduction order bit-identical to round-1 ->
//          counts stay exact vs reference).
// Phase 2: diagonal-ballot pair counting. Wave w owns diagonals d = w+1, w+5, ...
//          Lane l computes boolean b_d[i0+l] = |x[i]-x[i+d]| <= R; the v_cmp
//          ballot mask is reduced on the scalar pipe (lshr/and/bcnt1).
__global__ __launch_bounds__(256) void count_kernel(
    const float* __restrict__ pred, const float* __restrict__ targ,
    unsigned* __restrict__ partial) {
  const int s = blockIdx.y;
  const int c = blockIdx.x;
  const float* x = (s < 64) ? (pred + s * TLEN) : (targ + (s - 64) * TLEN);
  const int t = threadIdx.x;

  __shared__ float sx[TLEN + 64];   // +64 sentinel pad: max read idx 1084
  __shared__ float red[4];
  __shared__ unsigned redc[8];

  // ---- normalization (same op order as round-1) ----
  float v[4];
  float sum = 0.f;
#pragma unroll
  for (int k = 0; k < 4; k++) { v[k] = x[t + 256 * k]; sum += v[k]; }
  float wsum = wave_sum_f(sum);
  if ((t & 63) == 0) red[t >> 6] = wsum;
  __syncthreads();
  const float mean = (red[0] + red[1] + red[2] + red[3]) / (float)TLEN;
  __syncthreads();
  float ssq = 0.f;
#pragma unroll
  for (int k = 0; k < 4; k++) { float d0 = v[k] - mean; ssq += d0 * d0; }
  wsum = wave_sum_f(ssq);
  if ((t & 63) == 0) red[t >> 6] = wsum;
  __syncthreads();
  const float var = (red[0] + red[1] + red[2] + red[3]) / (float)(TLEN - 1);
  const float denom = sqrtf(var) + EPSN;
#pragma unroll
  for (int k = 0; k < 4; k++) sx[t + 256 * k] = (v[k] - mean) / denom;
  if (t < 64) sx[TLEN + t] = 1e30f;  // sentinel: |xi - 1e30| > R -> b = 0
  __syncthreads();

  // ---- diagonal ballot counting ----
  const int w = t >> 6;       // wave 0..3: owns d = w+1 step 4
  const int l = t & 63;
  const int i0 = 62 * c;      // chunk base row
  const float xi = sx[i0 + l];
  unsigned cm2 = 0, cm3 = 0;  // wave-uniform (SGPR) accumulators

  const int dmax  = 1021 - i0;  // last diagonal with a valid pair at k=i0
  const int dmain = 960 - i0;   // full-credit while 1021-i0-d >= 61
  int d = w + 1;
#pragma unroll 4
  for (; d <= dmain; d += 4) {
    const float y = sx[i0 + l + d];
    const unsigned long long m = __ballot(fabsf(xi - y) <= RTHR);
    const unsigned long long p = m & (m >> 1);
    cm2 += __popcll(p & MCRED);
    cm3 += __popcll(p & (m >> 2) & MCRED);
  }
  for (; d <= dmax; d += 4) {  // tail: diagonal ends inside this chunk
    const float y = sx[i0 + l + d];
    const unsigned long long m = __ballot(fabsf(xi - y) <= RTHR);
    const int rem = 1021 - i0 - d;  // 0..60: last valid pair bit
    const unsigned long long mask = (1ULL << (rem + 1)) - 1ULL;
    const unsigned long long p = m & (m >> 1);
    cm2 += __popcll(p & mask);
    cm3 += __popcll(p & (m >> 2) & mask);
  }

  if (l == 0) { redc[w] = cm2; redc[4 + w] = cm3; }
  __syncthreads();
  if (t == 0) {
    partial[(s * NCHUNK + c) * 2]     = redc[0] + redc[1] + redc[2] + redc[3];
    partial[(s * NCHUNK + c) * 2 + 1] = redc[4] + redc[5] + redc[6] + redc[7];
  }
}

// 128 threads: thread s -> signal s entropy; then MSE over the 64 channels.
__global__ __launch_bounds__(128) void final_kernel(
    const unsigned* __restrict__ partial, float* __restrict__ out) {
  __shared__ float ents[128];
  const int s = threadIdx.x;
  unsigned Sp = 0, St = 0;
  for (int c = 0; c < NCHUNK; c++) {
    Sp += partial[(s * NCHUNK + c) * 2];
    St += partial[(s * NCHUNK + c) * 2 + 1];
  }
  const unsigned cm  = (unsigned)NSAMP + 2u * Sp;  // diag (d=0) contributes N
  const unsigned cm1 = (unsigned)NSAMP + 2u * St;
  const float ratio = (float)cm1 / (float)(cm > 0u ? cm : 1u);
  const float e = -logf(fmaxf(ratio, 1e-30f));
  ents[s] = (cm > 0u && cm1 > 0u) ? e : 0.f;
  __syncthreads();
  if (s < 64) {
    const float d = ents[s] - ents[s + 64];
    const float sq = wave_sum_f(d * d);
    if (s == 0) out[0] = sq / 64.f;
  }
}

extern "C" void kernel_launch(void* const* d_in, const int* in_sizes, int n_in,
                              void* d_out, int out_size, void* d_ws, size_t ws_size,
                              hipStream_t stream) {
  const float* pred = (const float*)d_in[0];
  const float* targ = (const float*)d_in[1];
  unsigned* partial = (unsigned*)d_ws;  // NSIG*NCHUNK*2 u32 = 17.4 KB

  count_kernel<<<dim3(NCHUNK, NSIG), 256, 0, stream>>>(pred, targ, partial);
  final_kernel<<<1, 128, 0, stream>>>(partial, (float*)d_out);
}

// Round 3
// 79.512 us; speedup vs baseline: 1.2820x; 1.2820x over previous
//
#include <hip/hip_runtime.h>
#include <math.h>

static constexpr int TLEN  = 1024;  // signal length
static constexpr int NSAMP = 1022;  // N = T - M, M = 2
static constexpr int NSIG  = 128;   // 64 pred + 64 targ
static constexpr int NB    = 10;    // blocks per signal (40 wave-tasks / 4)
static constexpr float RTHR = 0.2f;
static constexpr float EPSN = 1e-8f;

__device__ __forceinline__ float wave_sum_f(float v) {
#pragma unroll
  for (int off = 32; off > 0; off >>= 1) v += __shfl_down(v, off);
  return v;
}
__device__ __forceinline__ unsigned wave_sum_u(unsigned v) {
#pragma unroll
  for (int off = 32; off > 0; off >>= 1) v += __shfl_down(v, off);
  return v;
}

// grid (NB, NSIG), 256 threads = 4 waves.
// Phase 1: in-block normalization, op-order IDENTICAL to rounds 1-2 (absmax
//          was exactly 0.0 -> do not perturb mean/denom rounding).
// Phase 2: wave-task = (64-diagonal block w) x (256-wide i-chunk).
//          Lane l owns diagonal d = 64w+1+l and rolls raw diffs df0/df1/df2
//          along i: per step 1 conflict-free ds_read + ~8 VALU ops.
//          max(|a|,|b|) <= R is exact, so counts are bit-robust.
__global__ __launch_bounds__(256) void count_kernel(
    const float* __restrict__ pred, const float* __restrict__ targ,
    unsigned* __restrict__ partial) {
  const int s = blockIdx.y;
  const int b = blockIdx.x;
  const float* x = (s < 64) ? (pred + s * TLEN) : (targ + (s - 64) * TLEN);
  const int t = threadIdx.x;

  __shared__ float sx[TLEN + 64];  // pad [1024,1088) = sentinels
  __shared__ float red[4];
  __shared__ unsigned redc[8];

  // ---- normalization (bit-identical to round-1/2) ----
  float v[4];
  float sum = 0.f;
#pragma unroll
  for (int k = 0; k < 4; k++) { v[k] = x[t + 256 * k]; sum += v[k]; }
  float wsum = wave_sum_f(sum);
  if ((t & 63) == 0) red[t >> 6] = wsum;
  __syncthreads();
  const float mean = (red[0] + red[1] + red[2] + red[3]) / (float)TLEN;
  __syncthreads();
  float ssq = 0.f;
#pragma unroll
  for (int k = 0; k < 4; k++) { float d0 = v[k] - mean; ssq += d0 * d0; }
  wsum = wave_sum_f(ssq);
  if ((t & 63) == 0) red[t >> 6] = wsum;
  __syncthreads();
  const float var = (red[0] + red[1] + red[2] + red[3]) / (float)(TLEN - 1);
  const float denom = sqrtf(var) + EPSN;
#pragma unroll
  for (int k = 0; k < 4; k++) sx[t + 256 * k] = (v[k] - mean) / denom;
  if (t < 64) sx[TLEN + t] = 1e30f;  // sentinel: never within R, never NaN
  __syncthreads();

  // ---- task decode: tid = b*4 + wave, 40 tasks/signal ----
  const int l = t & 63;
  int tid = b * 4 + (t >> 6);
  int w = 0;
  for (;;) {
    const int nc = (1021 - 64 * w + 255) >> 8;  // chunks in d-block w
    if (tid < nc) break;
    tid -= nc; w++;
  }
  const int lenw = 1021 - 64 * w;          // pairs on diagonal dmin
  const int dmin = 64 * w + 1;
  const int d    = dmin + l;               // this lane's diagonal
  const int i0   = tid << 8;
  const int i1   = min(i0 + 256, lenw);
  // all 64 lanes valid while i < lenw-63
  const int e0   = min(i1, max(i0, lenw - 63));

  // warm-up: df0 = x[i0]-x[i0+d], df1 = x[i0+1]-x[i0+1+d]
  float df0 = sx[i0] - sx[i0 + d];
  float df1 = sx[i0 + 1] - sx[i0 + 1 + d];
  unsigned cm2 = 0, cm3 = 0;

  int i = i0;
  // main: 64-unrolled, xi2 broadcast via v_readlane (keeps LDS pipe at 1 read/iter)
  for (; i + 64 <= e0; i += 64) {
    const int vxi = __float_as_int(sx[i + 2 + l]);
    const int yb = i + 2 + d;
#pragma unroll
    for (int u = 0; u < 64; u++) {
      const float xi2 = __int_as_float(__builtin_amdgcn_readlane(vxi, u));
      const float y2  = sx[yb + u];
      const float df2 = xi2 - y2;
      const float m2  = fmaxf(fabsf(df0), fabsf(df1));
      const float m3  = fmaxf(m2, fabsf(df2));
      cm2 += (m2 <= RTHR) ? 1u : 0u;
      cm3 += (m3 <= RTHR) ? 1u : 0u;
      df0 = df1; df1 = df2;
    }
  }
  for (; i < e0; i++) {  // remainder, unmasked
    const float xi2 = sx[i + 2];
    const float y2  = sx[i + 2 + d];
    const float df2 = xi2 - y2;
    const float m2  = fmaxf(fabsf(df0), fabsf(df1));
    const float m3  = fmaxf(m2, fabsf(df2));
    cm2 += (m2 <= RTHR) ? 1u : 0u;
    cm3 += (m3 <= RTHR) ? 1u : 0u;
    df0 = df1; df1 = df2;
  }
  for (; i < i1; i++) {  // ragged tail: lane valid iff i <= lenw-1-l
    const float xi2 = sx[i + 2];
    const float y2  = sx[i + 2 + d];
    const float df2 = xi2 - y2;
    const float m2  = fmaxf(fabsf(df0), fabsf(df1));
    const float m3  = fmaxf(m2, fabsf(df2));
    const unsigned ok = (i + l <= lenw - 1) ? 1u : 0u;
    cm2 += ok & ((m2 <= RTHR) ? 1u : 0u);
    cm3 += ok & ((m3 <= RTHR) ? 1u : 0u);
    df0 = df1; df1 = df2;
  }

  cm2 = wave_sum_u(cm2);
  cm3 = wave_sum_u(cm3);
  if (l == 0) { redc[t >> 6] = cm2; redc[4 + (t >> 6)] = cm3; }
  __syncthreads();
  if (t == 0) {
    partial[(s * NB + b) * 2]     = redc[0] + redc[1] + redc[2] + redc[3];
    partial[(s * NB + b) * 2 + 1] = redc[4] + redc[5] + redc[6] + redc[7];
  }
}

// 128 threads: thread s -> signal s entropy; then MSE over the 64 channels.
__global__ __launch_bounds__(128) void final_kernel(
    const unsigned* __restrict__ partial, float* __restrict__ out) {
  __shared__ float ents[128];
  const int s = threadIdx.x;
  unsigned Sp = 0, St = 0;
  for (int c = 0; c < NB; c++) {
    Sp += partial[(s * NB + c) * 2];
    St += partial[(s * NB + c) * 2 + 1];
  }
  const unsigned cm  = (unsigned)NSAMP + 2u * Sp;  // self-matches on diag
  const unsigned cm1 = (unsigned)NSAMP + 2u * St;
  const float ratio = (float)cm1 / (float)(cm > 0u ? cm : 1u);
  const float e = -logf(fmaxf(ratio, 1e-30f));
  ents[s] = (cm > 0u && cm1 > 0u) ? e : 0.f;
  __syncthreads();
  if (s < 64) {
    const float dd = ents[s] - ents[s + 64];
    const float sq = wave_sum_f(dd * dd);
    if (s == 0) out[0] = sq / 64.f;
  }
}

extern "C" void kernel_launch(void* const* d_in, const int* in_sizes, int n_in,
                              void* d_out, int out_size, void* d_ws, size_t ws_size,
                              hipStream_t stream) {
  const float* pred = (const float*)d_in[0];
  const float* targ = (const float*)d_in[1];
  unsigned* partial = (unsigned*)d_ws;  // NSIG*NB*2 u32 = 10.2 KB

  count_kernel<<<dim3(NB, NSIG), 256, 0, stream>>>(pred, targ, partial);
  final_kernel<<<1, 128, 0, stream>>>(partial, (float*)d_out);
}

// Round 4
// 71.634 us; speedup vs baseline: 1.4230x; 1.1100x over previous
//
#include <hip/hip_runtime.h>
#include <math.h>

static constexpr int TLEN  = 1024;  // signal length
static constexpr int NSAMP = 1022;  // N = T - M, M = 2
static constexpr int NSIG  = 128;   // 64 pred + 64 targ
static constexpr int NB    = 10;    // blocks per signal (40 wave-tasks / 4)
static constexpr int SXPAD = 1092;  // sx + sentinel pad (max read idx 1089)
static constexpr float RTHR = 0.2f;
static constexpr float EPSN = 1e-8f;

__device__ __forceinline__ float wave_sum_f(float v) {
#pragma unroll
  for (int off = 32; off > 0; off >>= 1) v += __shfl_down(v, off);
  return v;
}
__device__ __forceinline__ unsigned wave_sum_u(unsigned v) {
#pragma unroll
  for (int off = 32; off > 0; off >>= 1) v += __shfl_down(v, off);
  return v;
}

// push boolean (|df| <= R) into per-lane 32-bit shift register: mask = 2*mask + b
// exactly 2 VALU instructions (v_cmp -> vcc, v_addc reads vcc as the bit).
__device__ __forceinline__ void push_bool(unsigned& mask, float df, float rthr) {
  asm("v_cmp_le_f32 vcc, |%1|, %2\n\t"
      "v_addc_co_u32 %0, vcc, %0, %0, vcc"
      : "+v"(mask)
      : "v"(df), "s"(rthr)
      : "vcc");
}

// grid (NB, NSIG), 256 threads = 4 waves.
// Phase 1: in-block normalization, op-order IDENTICAL to rounds 1-3 (absmax
//          has been exactly 0.0 -> do not perturb mean/denom rounding).
// Phase 2: wave-task = (64-diagonal group w) x (256-wide start-chunk).
//          Lane l owns diagonal d = 64w+1+l. Booleans b[k]=|x[k]-x[k+d]|<=R
//          accumulate bit-serially; epilogue every 16 counts pairs/triples
//          via popcount. Sentinel pad (1e30) zeroes all out-of-range booleans;
//          the single real-data out-of-range pair (start 1022-d) is subtracted
//          by the per-task correction below.
__global__ __launch_bounds__(256) void count_kernel(
    const float* __restrict__ pred, const float* __restrict__ targ,
    unsigned* __restrict__ partial) {
  const int s = blockIdx.y;
  const int b = blockIdx.x;
  const float* x = (s < 64) ? (pred + s * TLEN) : (targ + (s - 64) * TLEN);
  const int t = threadIdx.x;

  __shared__ float sx[SXPAD];
  __shared__ float red[4];
  __shared__ unsigned redc[8];

  // ---- normalization (bit-identical to rounds 1-3) ----
  float v[4];
  float sum = 0.f;
#pragma unroll
  for (int k = 0; k < 4; k++) { v[k] = x[t + 256 * k]; sum += v[k]; }
  float wsum = wave_sum_f(sum);
  if ((t & 63) == 0) red[t >> 6] = wsum;
  __syncthreads();
  const float mean = (red[0] + red[1] + red[2] + red[3]) / (float)TLEN;
  __syncthreads();
  float ssq = 0.f;
#pragma unroll
  for (int k = 0; k < 4; k++) { float d0 = v[k] - mean; ssq += d0 * d0; }
  wsum = wave_sum_f(ssq);
  if ((t & 63) == 0) red[t >> 6] = wsum;
  __syncthreads();
  const float var = (red[0] + red[1] + red[2] + red[3]) / (float)(TLEN - 1);
  const float denom = sqrtf(var) + EPSN;
#pragma unroll
  for (int k = 0; k < 4; k++) sx[t + 256 * k] = (v[k] - mean) / denom;
  if (t < SXPAD - TLEN) sx[TLEN + t] = 1e30f;  // sentinel: never within R
  __syncthreads();

  // ---- task decode: tid = b*4 + wave, 40 tasks/signal ----
  const int l = t & 63;
  int tid = b * 4 + (t >> 6);
  int w = 0;
  for (;;) {
    const int nc = (1021 - 64 * w + 255) >> 8;  // 256-chunks in group w
    if (tid < nc) break;
    tid -= nc; w++;
  }
  const int len = 1021 - 64 * w;   // pair-start count for lane-0 diagonal
  const int d   = 64 * w + 1 + l;  // this lane's diagonal
  const int i0  = tid << 8;
  const int n   = min(256, len - i0);  // counting steps this task
  const int i1u = i0 + n;

  // warm-up: seed mask with b[i0], b[i0+1]
  unsigned mask = 0;
  push_bool(mask, sx[i0] - sx[i0 + d], RTHR);
  push_bool(mask, sx[i0 + 1] - sx[i0 + 1 + d], RTHR);

  unsigned cm2 = 0, cm3 = 0;
  const int nblk = (n + 63) >> 6;
  for (int blk = 0; blk < nblk; ++blk) {
    const int kb = i0 + 2 + (blk << 6);
    const int vxi = __float_as_int(sx[kb + l]);  // 64 uniform xi's for readlane
    const int ybase = kb + d;
    const int done0 = blk << 6;
#pragma unroll
    for (int sub = 0; sub < 4; ++sub) {
#pragma unroll
      for (int u = 0; u < 16; ++u) {
        const int lane = (sub << 4) | u;
        const float xi2 = __int_as_float(__builtin_amdgcn_readlane(vxi, lane));
        const float df = xi2 - sx[ybase + lane];
        push_bool(mask, df, RTHR);
      }
      // epilogue: count 16 pair/triple starts (newest at bit 0)
      int vv = n - (done0 + (sub << 4));
      vv = vv < 0 ? 0 : (vv > 16 ? 16 : vv);
      const unsigned vm = (0xFFFFu << (16 - vv)) & 0xFFFFu;
      const unsigned q = (mask >> 1) & (mask >> 2) & vm;
      cm2 += __popc(q);
      cm3 += __popc(q & mask);
    }
  }

  // correction: the single out-of-range pair built from real data
  // (start 1022-d uses x[1022],x[1023]); counted iff it fell in this task.
  const int ibad = 1022 - d;
  if (ibad >= i0 && ibad < i1u) {
    if (fabsf(sx[ibad] - sx[1022]) <= RTHR &&
        fabsf(sx[ibad + 1] - sx[1023]) <= RTHR)
      cm2 -= 1u;
  }

  cm2 = wave_sum_u(cm2);
  cm3 = wave_sum_u(cm3);
  if (l == 0) { redc[t >> 6] = cm2; redc[4 + (t >> 6)] = cm3; }
  __syncthreads();
  if (t == 0) {
    partial[(s * NB + b) * 2]     = redc[0] + redc[1] + redc[2] + redc[3];
    partial[(s * NB + b) * 2 + 1] = redc[4] + redc[5] + redc[6] + redc[7];
  }
}

// 128 threads: thread s -> signal s entropy; then MSE over the 64 channels.
__global__ __launch_bounds__(128) void final_kernel(
    const unsigned* __restrict__ partial, float* __restrict__ out) {
  __shared__ float ents[128];
  const int s = threadIdx.x;
  unsigned Sp = 0, St = 0;
  for (int c = 0; c < NB; c++) {
    Sp += partial[(s * NB + c) * 2];
    St += partial[(s * NB + c) * 2 + 1];
  }
  const unsigned cm  = (unsigned)NSAMP + 2u * Sp;  // self-matches on diagonal
  const unsigned cm1 = (unsigned)NSAMP + 2u * St;
  const float ratio = (float)cm1 / (float)(cm > 0u ? cm : 1u);
  const float e = -logf(fmaxf(ratio, 1e-30f));
  ents[s] = (cm > 0u && cm1 > 0u) ? e : 0.f;
  __syncthreads();
  if (s < 64) {
    const float dd = ents[s] - ents[s + 64];
    const float sq = wave_sum_f(dd * dd);
    if (s == 0) out[0] = sq / 64.f;
  }
}

extern "C" void kernel_launch(void* const* d_in, const int* in_sizes, int n_in,
                              void* d_out, int out_size, void* d_ws, size_t ws_size,
                              hipStream_t stream) {
  const float* pred = (const float*)d_in[0];
  const float* targ = (const float*)d_in[1];
  unsigned* partial = (unsigned*)d_ws;  // NSIG*NB*2 u32 = 10.2 KB

  count_kernel<<<dim3(NB, NSIG), 256, 0, stream>>>(pred, targ, partial);
  final_kernel<<<1, 128, 0, stream>>>(partial, (float*)d_out);
}

// Round 5
// 69.211 us; speedup vs baseline: 1.4728x; 1.0350x over previous
//
#include <hip/hip_runtime.h>
#include <math.h>

static constexpr int TLEN  = 1024;  // signal length
static constexpr int NSAMP = 1022;  // N = T - M, M = 2
static constexpr int NSIG  = 128;   // 64 pred + 64 targ
static constexpr int NB    = 10;    // blocks per signal (40 wave-tasks / 4)
static constexpr int SXPAD = 1368;  // sx + sentinel pad (max read idx ~1343)
static constexpr float RTHR = 0.2f;
static constexpr float EPSN = 1e-8f;

__device__ __forceinline__ float wave_sum_f(float v) {
#pragma unroll
  for (int off = 32; off > 0; off >>= 1) v += __shfl_down(v, off);
  return v;
}
__device__ __forceinline__ unsigned wave_sum_u(unsigned v) {
#pragma unroll
  for (int off = 32; off > 0; off >>= 1) v += __shfl_down(v, off);
  return v;
}

// push boolean (|df| <= R) into per-lane 32-bit shift register: mask = 2*mask + b
__device__ __forceinline__ void push_bool(unsigned& mask, float df, float rthr) {
  asm("v_cmp_le_f32 vcc, |%1|, %2\n\t"
      "v_addc_co_u32 %0, vcc, %0, %0, vcc"
      : "+v"(mask)
      : "v"(df), "s"(rthr)
      : "vcc");
}

// One wave-task: lane l owns diagonal d (all lanes share d mod 4 -> OFF is
// wave-uniform and compile-time). Booleans b[k]=|x[k]-x[k+d]|<=R accumulate
// bit-serially (2 VALU); y comes from a rolling 5xfloat4 aligned window:
// exactly one ds_read_b128 per 4 booleans. Epilogue every 16 counts pair/
// triple starts via popcount (identical logic to round 4, absmax 0.0).
template <int OFF>
__device__ __forceinline__ void run_task(const float* sx, const float4* sx4,
                                         int i0, int n, int d, int l,
                                         unsigned& cm2, unsigned& cm3) {
  unsigned mask = 0;
  push_bool(mask, sx[i0] - sx[i0 + d], RTHR);
  push_bool(mask, sx[i0 + 1] - sx[i0 + 1 + d], RTHR);

  int B = (i0 + 2 + d) >> 2;  // float4 index; 4B + OFF == first y index
  float4 c0;
  if (OFF != 0) c0 = sx4[B];  // carried low window reg

  const int nblk = (n + 63) >> 6;
  for (int blk = 0; blk < nblk; ++blk) {
    const int kb = i0 + 2 + (blk << 6);
    const int vxi = __float_as_int(sx[kb + l]);  // 64 xi's for readlane
    const int done0 = blk << 6;
#pragma unroll
    for (int sub = 0; sub < 4; ++sub) {
      float f[20];
      if (OFF == 0) {
        *(float4*)&f[0]  = sx4[B];
        *(float4*)&f[4]  = sx4[B + 1];
        *(float4*)&f[8]  = sx4[B + 2];
        *(float4*)&f[12] = sx4[B + 3];
      } else {
        *(float4*)&f[0]  = c0;
        *(float4*)&f[4]  = sx4[B + 1];
        *(float4*)&f[8]  = sx4[B + 2];
        *(float4*)&f[12] = sx4[B + 3];
        *(float4*)&f[16] = sx4[B + 4];
        c0 = *(float4*)&f[16];
      }
      B += 4;
#pragma unroll
      for (int u = 0; u < 16; ++u) {
        const int lane = (sub << 4) | u;
        const float xi2 = __int_as_float(__builtin_amdgcn_readlane(vxi, lane));
        push_bool(mask, xi2 - f[OFF + u], RTHR);
      }
      int vv = n - (done0 + (sub << 4));
      vv = vv < 0 ? 0 : (vv > 16 ? 16 : vv);
      const unsigned vm = (0xFFFFu << (16 - vv)) & 0xFFFFu;
      const unsigned q = (mask >> 1) & (mask >> 2) & vm;
      cm2 += __popc(q);
      cm3 += __popc(q & mask);
    }
  }

  // correction: the single out-of-range pair built from real data
  // (start 1022-d uses x[1022],x[1023]); counted iff it fell in this task.
  const int ibad = 1022 - d;
  if (ibad >= i0 && ibad < i0 + n) {
    if (fabsf(sx[ibad] - sx[1022]) <= RTHR &&
        fabsf(sx[ibad + 1] - sx[1023]) <= RTHR)
      cm2 -= 1u;
  }
}

// grid (NB, NSIG), 256 threads = 4 waves.
// Phase 1: in-block normalization, op-order IDENTICAL to rounds 1-4 (absmax
//          has been exactly 0.0 -> do not perturb mean/denom rounding).
// Phase 2: 40 wave-tasks/signal: residue class rr = tid/10 + 1 (d mod 4
//          uniform per wave), group g + 256-wide start-chunk c from tid%10.
//          Lane l: d = 256g + 4l + rr. Sentinel pad (1e30) falsifies all
//          out-of-range booleans; phantom lanes (d > 1021) count 0.
__global__ __launch_bounds__(256) void count_kernel(
    const float* __restrict__ pred, const float* __restrict__ targ,
    unsigned* __restrict__ partial) {
  const int s = blockIdx.y;
  const int b = blockIdx.x;
  const float* x = (s < 64) ? (pred + s * TLEN) : (targ + (s - 64) * TLEN);
  const int t = threadIdx.x;

  __shared__ __align__(16) float sx[SXPAD];
  __shared__ float red[4];
  __shared__ unsigned redc[8];

  // ---- normalization (bit-identical to rounds 1-4) ----
  float v[4];
  float sum = 0.f;
#pragma unroll
  for (int k = 0; k < 4; k++) { v[k] = x[t + 256 * k]; sum += v[k]; }
  float wsum = wave_sum_f(sum);
  if ((t & 63) == 0) red[t >> 6] = wsum;
  __syncthreads();
  const float mean = (red[0] + red[1] + red[2] + red[3]) / (float)TLEN;
  __syncthreads();
  float ssq = 0.f;
#pragma unroll
  for (int k = 0; k < 4; k++) { float d0 = v[k] - mean; ssq += d0 * d0; }
  wsum = wave_sum_f(ssq);
  if ((t & 63) == 0) red[t >> 6] = wsum;
  __syncthreads();
  const float var = (red[0] + red[1] + red[2] + red[3]) / (float)(TLEN - 1);
  const float denom = sqrtf(var) + EPSN;
#pragma unroll
  for (int k = 0; k < 4; k++) sx[t + 256 * k] = (v[k] - mean) / denom;
  for (int k = TLEN + t; k < SXPAD; k += 256) sx[k] = 1e30f;  // sentinels
  __syncthreads();

  // ---- task decode (wave-uniform): tid -> (rr, g, c) ----
  const int l = t & 63;
  const int tid = b * 4 + (t >> 6);         // 0..39
  const int rr = tid / 10 + 1;              // residue class 1..4 (d mod 4)
  const int t2 = tid % 10;
  int g, c;
  if (t2 < 4)      { g = 0; c = t2; }
  else if (t2 < 7) { g = 1; c = t2 - 4; }
  else if (t2 < 9) { g = 2; c = t2 - 7; }
  else             { g = 3; c = 0; }
  const int d0  = 256 * g + rr;             // lane-0 diagonal (longest)
  const int len0 = NSAMP - d0;              // lane-0 pair-start count
  const int i0  = 256 * c;
  const int n   = min(256, len0 - i0);      // uniform steps this task
  const int d   = d0 + 4 * l;               // this lane's diagonal

  unsigned cm2 = 0, cm3 = 0;
  const float4* sx4 = (const float4*)sx;
  switch (rr) {  // OFF = (2 + rr) & 3, wave-uniform branch
    case 1: run_task<3>(sx, sx4, i0, n, d, l, cm2, cm3); break;
    case 2: run_task<0>(sx, sx4, i0, n, d, l, cm2, cm3); break;
    case 3: run_task<1>(sx, sx4, i0, n, d, l, cm2, cm3); break;
    default: run_task<2>(sx, sx4, i0, n, d, l, cm2, cm3); break;
  }

  cm2 = wave_sum_u(cm2);
  cm3 = wave_sum_u(cm3);
  if (l == 0) { redc[t >> 6] = cm2; redc[4 + (t >> 6)] = cm3; }
  __syncthreads();
  if (t == 0) {
    partial[(s * NB + b) * 2]     = redc[0] + redc[1] + redc[2] + redc[3];
    partial[(s * NB + b) * 2 + 1] = redc[4] + redc[5] + redc[6] + redc[7];
  }
}

// 128 threads: thread s -> signal s entropy; then MSE over the 64 channels.
__global__ __launch_bounds__(128) void final_kernel(
    const unsigned* __restrict__ partial, float* __restrict__ out) {
  __shared__ float ents[128];
  const int s = threadIdx.x;
  unsigned Sp = 0, St = 0;
  for (int c = 0; c < NB; c++) {
    Sp += partial[(s * NB + c) * 2];
    St += partial[(s * NB + c) * 2 + 1];
  }
  const unsigned cm  = (unsigned)NSAMP + 2u * Sp;  // self-matches on diagonal
  const unsigned cm1 = (unsigned)NSAMP + 2u * St;
  const float ratio = (float)cm1 / (float)(cm > 0u ? cm : 1u);
  const float e = -logf(fmaxf(ratio, 1e-30f));
  ents[s] = (cm > 0u && cm1 > 0u) ? e : 0.f;
  __syncthreads();
  if (s < 64) {
    const float dd = ents[s] - ents[s + 64];
    const float sq = wave_sum_f(dd * dd);
    if (s == 0) out[0] = sq / 64.f;
  }
}

extern "C" void kernel_launch(void* const* d_in, const int* in_sizes, int n_in,
                              void* d_out, int out_size, void* d_ws, size_t ws_size,
                              hipStream_t stream) {
  const float* pred = (const float*)d_in[0];
  const float* targ = (const float*)d_in[1];
  unsigned* partial = (unsigned*)d_ws;  // NSIG*NB*2 u32 = 10.2 KB

  count_kernel<<<dim3(NB, NSIG), 256, 0, stream>>>(pred, targ, partial);
  final_kernel<<<1, 128, 0, stream>>>(partial, (float*)d_out);
}